// Round 3
// baseline (554.718 us; speedup 1.0000x reference)
//
#include <hip/hip_runtime.h>
#include <hip/hip_bf16.h>
#include <stdint.h>

#define TOK   16384
#define DIM   256
#define HIDN  1024
#define OUTD  256
#define NEXP  8
#define NSH   3
#define TM    64

typedef short bf16x8  __attribute__((ext_vector_type(8)));
typedef float f32x4   __attribute__((ext_vector_type(4)));
typedef short short4v __attribute__((ext_vector_type(4)));

// ---- workspace layout (bytes, all 256-aligned) ----
constexpr size_t XB_OFF   = 0;                                        // T*D bf16
constexpr size_t W1P_OFF  = XB_OFF  + (size_t)TOK*DIM*2;              // 11*D*HID bf16 packed
constexpr size_t W2P_OFF  = W1P_OFF + (size_t)(NSH+NEXP)*DIM*HIDN*2;  // 11*HID*O bf16 packed
constexpr size_t WTS_OFF  = W2P_OFF + (size_t)(NSH+NEXP)*HIDN*OUTD*2; // T*2 fp32 (0.5-scaled)
constexpr size_t IDS_OFF  = WTS_OFF + (size_t)TOK*2*4;                // T*2 int32
constexpr size_t CNT_OFF  = IDS_OFF + (size_t)TOK*2*4;                // E int32 (+pad)
constexpr size_t LTOK_OFF = CNT_OFF + 256;                            // E*T int32
constexpr size_t LW_OFF   = LTOK_OFF + (size_t)NEXP*TOK*4;            // E*T fp32
constexpr size_t WS_NEED  = LW_OFF + (size_t)NEXP*TOK*4;

__device__ __forceinline__ unsigned short f2bf(float f) {
    __hip_bfloat16 h = __float2bfloat16(f);
    return *reinterpret_cast<unsigned short*>(&h);
}

__device__ __forceinline__ f32x4 mfma16(bf16x8 a, bf16x8 b, f32x4 c) {
    return __builtin_amdgcn_mfma_f32_16x16x32_bf16(a, b, c, 0, 0, 0);
}

// XOR swizzles: spread 8 consecutive rows across 8 distinct 16B slots.
// X tile: 64 rows x 256 bf16, row stride 512B.
__device__ __forceinline__ int xswz(int row, int colb) {
    return ((row << 9) + colb) ^ ((row & 7) << 4);
}
// H half-tile: 64 rows x 512 bf16, row stride 1024B.
__device__ __forceinline__ int hswz(int row, int colb) {
    return ((row << 10) + colb) ^ ((row & 7) << 4);
}

// ---- fp32 -> bf16 of X, row-major preserved ----
__global__ void k_convert_x(const float* __restrict__ x, short* __restrict__ xb) {
    int i = blockIdx.x * 256 + threadIdx.x;             // 4 elems per thread
    float4 v = reinterpret_cast<const float4*>(x)[i];
    short4v o;
    o[0] = (short)f2bf(v.x); o[1] = (short)f2bf(v.y);
    o[2] = (short)f2bf(v.z); o[3] = (short)f2bf(v.w);
    reinterpret_cast<short4v*>(xb)[i] = o;
}

// ---- fp32 weights -> bf16 packed in MFMA B-fragment order ----
// packed elem offset = ((kt*NT + nt)*64 + lane)*8 + j ; n=nt*16+(lane&15),
// k = kt*32 + 8*(lane>>4) + j.
__global__ void k_convert_w(const float* __restrict__ sw1, const float* __restrict__ iw1,
                            const float* __restrict__ sw2, const float* __restrict__ iw2,
                            short* __restrict__ w1p, short* __restrict__ w2p) {
    int gid = blockIdx.x * 256 + threadIdx.x;
    const int G1 = (NSH+NEXP) * (DIM/32) * (HIDN/16) * 64;   // 360448
    bool isW1 = gid < G1;
    int g = isW1 ? gid : gid - G1;
    int lane = g & 63;
    int gg = g >> 6;
    int NT = isW1 ? (HIDN/16) : (OUTD/16);
    int KT = isW1 ? (DIM/32)  : (HIDN/32);
    int nt = gg % NT; gg /= NT;
    int kt = gg % KT;
    int slot = gg / KT;
    int k = kt*32 + ((lane >> 4) << 3);
    int n = nt*16 + (lane & 15);
    int Nd = isW1 ? HIDN : OUTD;
    const float* src;
    if (isW1) src = (slot < NSH) ? sw1 + (size_t)slot*DIM*HIDN  : iw1 + (size_t)(slot-NSH)*DIM*HIDN;
    else      src = (slot < NSH) ? sw2 + (size_t)slot*HIDN*OUTD : iw2 + (size_t)(slot-NSH)*HIDN*OUTD;
    bf16x8 o;
    #pragma unroll
    for (int j = 0; j < 8; ++j) o[j] = (short)f2bf(src[(size_t)(k + j)*Nd + n]);
    short* dst = isW1 ? w1p : w2p;
    reinterpret_cast<bf16x8*>(dst)[g] = o;
}

// ---- gating: fp32-exact logits, top-2, renormalized, pre-scaled by 0.5 ----
__global__ void k_gate(const float* __restrict__ x, const float* __restrict__ gw,
                       const float* __restrict__ gb, float* __restrict__ wts,
                       int* __restrict__ ids) {
    int wid = threadIdx.x >> 6, lane = threadIdx.x & 63;
    int t = blockIdx.x * 4 + wid;
    const float* xr = x + (size_t)t * DIM;
    float acc[NEXP] = {0.f,0.f,0.f,0.f,0.f,0.f,0.f,0.f};
    #pragma unroll
    for (int i = 0; i < DIM/64; ++i) {
        int d = i*64 + lane;
        float xv = xr[d];
        const float* g = gw + (size_t)d * NEXP;
        #pragma unroll
        for (int e = 0; e < NEXP; ++e) acc[e] = fmaf(xv, g[e], acc[e]);
    }
    #pragma unroll
    for (int off = 32; off; off >>= 1) {
        #pragma unroll
        for (int e = 0; e < NEXP; ++e) acc[e] += __shfl_xor(acc[e], off, 64);
    }
    if (lane == 0) {
        float l[NEXP];
        #pragma unroll
        for (int e = 0; e < NEXP; ++e) l[e] = acc[e] + gb[e];
        int e0 = 0; float v0 = l[0];
        #pragma unroll
        for (int e = 1; e < NEXP; ++e) if (l[e] > v0) { v0 = l[e]; e0 = e; }
        int e1 = -1; float v1 = -1e30f;
        #pragma unroll
        for (int e = 0; e < NEXP; ++e) if (e != e0 && l[e] > v1) { v1 = l[e]; e1 = e; }
        float r = expf(v1 - v0);              // <= 1
        float w0 = 0.5f / (1.f + r);
        float w1 = 0.5f * r / (1.f + r);
        ids[2*t]   = e0;  ids[2*t+1] = e1;
        wts[2*t]   = w0;  wts[2*t+1] = w1;
    }
}

// ---- build per-expert token lists ----
__global__ void k_route(const int* __restrict__ ids, const float* __restrict__ wts,
                        int* __restrict__ cnt, int* __restrict__ ltok,
                        float* __restrict__ lw) {
    int t = blockIdx.x * 256 + threadIdx.x;
    #pragma unroll
    for (int k = 0; k < 2; ++k) {
        int e = ids[2*t + k];
        int p = atomicAdd(&cnt[e], 1);
        ltok[(size_t)e*TOK + p] = t;
        lw  [(size_t)e*TOK + p] = wts[2*t + k];
    }
}

// ---- shared experts: 64 tokens/block, 16 waves, H in LDS halves ----
__global__ __launch_bounds__(1024, 4) void k_shared(
    const short* __restrict__ xb, const short* __restrict__ w1p, const short* __restrict__ w2p,
    const float* __restrict__ sb1, const float* __restrict__ sb2,
    const float* __restrict__ obj, float* __restrict__ out)
{
    __shared__ __align__(16) char lds[98304];   // [0,32K): X tile, [32K,96K): H half
    char* xs = lds;
    char* hs = lds + 32768;
    const int t0   = blockIdx.x * TM;
    const int tid  = threadIdx.x;
    const int w    = tid >> 6;
    const int lane = tid & 63;
    const int lrow = lane & 15;
    const int g    = lane >> 4;

    // stage X tile (64 x 256 bf16) into swizzled LDS: 2 x 16B per thread
    {
        int c0 = tid * 2;
        int row = c0 >> 5, col16 = c0 & 31;
        const bf16x8* src = reinterpret_cast<const bf16x8*>(
            xb + (size_t)(t0 + row) * DIM + col16 * 8);
        bf16x8 v0 = src[0];
        bf16x8 v1 = src[1];
        *reinterpret_cast<bf16x8*>(xs + xswz(row, col16*16))      = v0;
        *reinterpret_cast<bf16x8*>(xs + xswz(row, col16*16 + 16)) = v1;
    }
    __syncthreads();

    f32x4 acc2[4] = {};                       // persists across experts/halves
    for (int s = 0; s < NSH; ++s) {
        const short* W1 = w1p + (size_t)s * DIM * HIDN;
        const short* W2 = w2p + (size_t)s * HIDN * OUTD;
        #pragma unroll
        for (int h = 0; h < 2; ++h) {
            // ---- phase A: H[64 x 512] half, wave owns 32 cols (2 nt) ----
            const int ntb = h*32 + w*2;       // global nt of this wave's 2 tiles
            f32x4 acc1[4][2] = {};
            bf16x8 Bn0 = *reinterpret_cast<const bf16x8*>(W1 + ((size_t)(0*64 + ntb  )*64 + lane)*8);
            bf16x8 Bn1 = *reinterpret_cast<const bf16x8*>(W1 + ((size_t)(0*64 + ntb+1)*64 + lane)*8);
            for (int kt = 0; kt < DIM/32; ++kt) {
                bf16x8 B0 = Bn0, B1 = Bn1;
                if (kt < DIM/32 - 1) {
                    Bn0 = *reinterpret_cast<const bf16x8*>(W1 + ((size_t)((kt+1)*64 + ntb  )*64 + lane)*8);
                    Bn1 = *reinterpret_cast<const bf16x8*>(W1 + ((size_t)((kt+1)*64 + ntb+1)*64 + lane)*8);
                }
                bf16x8 a[4];
                #pragma unroll
                for (int m = 0; m < 4; ++m)
                    a[m] = *reinterpret_cast<const bf16x8*>(xs + xswz(m*16 + lrow, kt*64 + g*16));
                #pragma unroll
                for (int m = 0; m < 4; ++m) {
                    acc1[m][0] = mfma16(a[m], B0, acc1[m][0]);
                    acc1[m][1] = mfma16(a[m], B1, acc1[m][1]);
                }
            }
            __syncthreads();                  // prev phase-B readers done
            // write H half: relu(acc1 + b1) * 0.5*obj, bf16 swizzled
            #pragma unroll
            for (int ntl = 0; ntl < 2; ++ntl) {
                int colh = w*32 + ntl*16 + lrow;
                float bias = sb1[s*HIDN + h*512 + colh];
                #pragma unroll
                for (int m = 0; m < 4; ++m) {
                    #pragma unroll
                    for (int r = 0; r < 4; ++r) {
                        int row = m*16 + g*4 + r;
                        float tw = 0.5f * obj[(size_t)(t0 + row)*NSH + s];
                        float v = fmaxf(acc1[m][ntl][r] + bias, 0.f) * tw;
                        *reinterpret_cast<unsigned short*>(hs + hswz(row, colh*2)) = f2bf(v);
                    }
                }
            }
            __syncthreads();
            // ---- phase B: O partial over this half's 512 K, wave owns 16 cols ----
            bf16x8 Bn = *reinterpret_cast<const bf16x8*>(W2 + ((size_t)((h*16+0)*16 + w)*64 + lane)*8);
            for (int kt = 0; kt < 16; ++kt) {
                bf16x8 B = Bn;
                if (kt < 15)
                    Bn = *reinterpret_cast<const bf16x8*>(W2 + ((size_t)((h*16+kt+1)*16 + w)*64 + lane)*8);
                bf16x8 a[4];
                #pragma unroll
                for (int m = 0; m < 4; ++m)
                    a[m] = *reinterpret_cast<const bf16x8*>(hs + hswz(m*16 + lrow, kt*64 + g*16));
                #pragma unroll
                for (int m = 0; m < 4; ++m)
                    acc2[m] = mfma16(a[m], B, acc2[m]);
            }
            __syncthreads();                  // before next half overwrites H
        }
    }
    // epilogue: + sum_s 0.5*obj*b2, non-atomic store
    const int col = w*16 + lrow;
    #pragma unroll
    for (int m = 0; m < 4; ++m) {
        #pragma unroll
        for (int r = 0; r < 4; ++r) {
            int row = m*16 + g*4 + r;
            int t = t0 + row;
            float v = acc2[m][r];
            #pragma unroll
            for (int s = 0; s < NSH; ++s)
                v += 0.5f * obj[(size_t)t*NSH + s] * sb2[s*OUTD + col];
            out[(size_t)t*OUTD + col] = v;
        }
    }
}

// ---- independent experts: gathered 64-token chunks, same structure ----
__global__ __launch_bounds__(1024, 4) void k_ind(
    const short* __restrict__ xb, const short* __restrict__ w1p, const short* __restrict__ w2p,
    const float* __restrict__ ib1, const float* __restrict__ ib2,
    const int* __restrict__ cnt, const int* __restrict__ ltok, const float* __restrict__ lw,
    float* __restrict__ out)
{
    __shared__ __align__(16) char lds[98304];
    char* xs = lds;
    char* hs = lds + 32768;
    const int e  = blockIdx.y;
    const int n0 = blockIdx.x * TM;
    const int count = cnt[e];
    if (n0 >= count) return;
    const short* W1 = w1p + (size_t)(NSH + e) * DIM * HIDN;
    const short* W2 = w2p + (size_t)(NSH + e) * HIDN * OUTD;
    const int* el = ltok + (size_t)e*TOK;
    const float* ew = lw + (size_t)e*TOK;
    const int tid  = threadIdx.x;
    const int w    = tid >> 6;
    const int lane = tid & 63;
    const int lrow = lane & 15;
    const int g    = lane >> 4;

    // gather-stage X rows for this chunk
    {
        int c0 = tid * 2;
        int row = c0 >> 5, col16 = c0 & 31;
        int tok = el[min(n0 + row, count - 1)];
        const bf16x8* src = reinterpret_cast<const bf16x8*>(
            xb + (size_t)tok * DIM + col16 * 8);
        bf16x8 v0 = src[0];
        bf16x8 v1 = src[1];
        *reinterpret_cast<bf16x8*>(xs + xswz(row, col16*16))      = v0;
        *reinterpret_cast<bf16x8*>(xs + xswz(row, col16*16 + 16)) = v1;
    }
    __syncthreads();

    f32x4 acc2[4] = {};
    #pragma unroll
    for (int h = 0; h < 2; ++h) {
        const int ntb = h*32 + w*2;
        f32x4 acc1[4][2] = {};
        bf16x8 Bn0 = *reinterpret_cast<const bf16x8*>(W1 + ((size_t)(0*64 + ntb  )*64 + lane)*8);
        bf16x8 Bn1 = *reinterpret_cast<const bf16x8*>(W1 + ((size_t)(0*64 + ntb+1)*64 + lane)*8);
        for (int kt = 0; kt < DIM/32; ++kt) {
            bf16x8 B0 = Bn0, B1 = Bn1;
            if (kt < DIM/32 - 1) {
                Bn0 = *reinterpret_cast<const bf16x8*>(W1 + ((size_t)((kt+1)*64 + ntb  )*64 + lane)*8);
                Bn1 = *reinterpret_cast<const bf16x8*>(W1 + ((size_t)((kt+1)*64 + ntb+1)*64 + lane)*8);
            }
            bf16x8 a[4];
            #pragma unroll
            for (int m = 0; m < 4; ++m)
                a[m] = *reinterpret_cast<const bf16x8*>(xs + xswz(m*16 + lrow, kt*64 + g*16));
            #pragma unroll
            for (int m = 0; m < 4; ++m) {
                acc1[m][0] = mfma16(a[m], B0, acc1[m][0]);
                acc1[m][1] = mfma16(a[m], B1, acc1[m][1]);
            }
        }
        __syncthreads();
        #pragma unroll
        for (int ntl = 0; ntl < 2; ++ntl) {
            int colh = w*32 + ntl*16 + lrow;
            float bias = ib1[(size_t)e*HIDN + h*512 + colh];
            #pragma unroll
            for (int m = 0; m < 4; ++m) {
                #pragma unroll
                for (int r = 0; r < 4; ++r) {
                    int row = m*16 + g*4 + r;
                    int p = n0 + row;
                    float tw = (p < count) ? ew[p] : 0.f;   // already 0.5-scaled
                    float v = fmaxf(acc1[m][ntl][r] + bias, 0.f) * tw;
                    *reinterpret_cast<unsigned short*>(hs + hswz(row, colh*2)) = f2bf(v);
                }
            }
        }
        __syncthreads();
        bf16x8 Bn = *reinterpret_cast<const bf16x8*>(W2 + ((size_t)((h*16+0)*16 + w)*64 + lane)*8);
        for (int kt = 0; kt < 16; ++kt) {
            bf16x8 B = Bn;
            if (kt < 15)
                Bn = *reinterpret_cast<const bf16x8*>(W2 + ((size_t)((h*16+kt+1)*16 + w)*64 + lane)*8);
            bf16x8 a[4];
            #pragma unroll
            for (int m = 0; m < 4; ++m)
                a[m] = *reinterpret_cast<const bf16x8*>(hs + hswz(m*16 + lrow, kt*64 + g*16));
            #pragma unroll
            for (int m = 0; m < 4; ++m)
                acc2[m] = mfma16(a[m], B, acc2[m]);
        }
        __syncthreads();
    }
    const int col = w*16 + lrow;
    #pragma unroll
    for (int m = 0; m < 4; ++m) {
        #pragma unroll
        for (int r = 0; r < 4; ++r) {
            int row = m*16 + g*4 + r;
            int p = n0 + row;
            if (p < count) {
                int t = el[p];
                float v = acc2[m][r] + ew[p] * ib2[(size_t)e*OUTD + col];
                atomicAdd(&out[(size_t)t*OUTD + col], v);
            }
        }
    }
}

extern "C" void kernel_launch(void* const* d_in, const int* in_sizes, int n_in,
                              void* d_out, int out_size, void* d_ws, size_t ws_size,
                              hipStream_t stream) {
    const float* x   = (const float*)d_in[0];
    const float* obj = (const float*)d_in[1];
    const float* gw  = (const float*)d_in[2];
    const float* gb  = (const float*)d_in[3];
    const float* sw1 = (const float*)d_in[4];
    const float* sb1 = (const float*)d_in[5];
    const float* sw2 = (const float*)d_in[6];
    const float* sb2 = (const float*)d_in[7];
    const float* iw1 = (const float*)d_in[8];
    const float* ib1 = (const float*)d_in[9];
    const float* iw2 = (const float*)d_in[10];
    const float* ib2 = (const float*)d_in[11];
    float* out = (float*)d_out;
    char* ws = (char*)d_ws;
    if (ws_size < WS_NEED) return;

    short* xb   = (short*)(ws + XB_OFF);
    short* w1p  = (short*)(ws + W1P_OFF);
    short* w2p  = (short*)(ws + W2P_OFF);
    float* wts  = (float*)(ws + WTS_OFF);
    int*   ids  = (int*)  (ws + IDS_OFF);
    int*   cnt  = (int*)  (ws + CNT_OFF);
    int*   ltok = (int*)  (ws + LTOK_OFF);
    float* lwt  = (float*)(ws + LW_OFF);

    hipMemsetAsync(ws + CNT_OFF, 0, 256, stream);
    k_convert_x<<<(TOK*DIM/4)/256, 256, 0, stream>>>(x, xb);
    {
        const int G = (NSH+NEXP) * ((DIM/32)*(HIDN/16) + (HIDN/32)*(OUTD/16)) * 64;
        k_convert_w<<<G/256, 256, 0, stream>>>(sw1, iw1, sw2, iw2, w1p, w2p);
    }
    k_gate<<<TOK/4, 256, 0, stream>>>(x, gw, gb, wts, ids);
    k_route<<<TOK/256, 256, 0, stream>>>(ids, wts, cnt, ltok, lwt);
    k_shared<<<TOK/TM, 1024, 0, stream>>>(xb, w1p, w2p, sb1, sb2, obj, out);
    k_ind<<<dim3(TOK/TM, NEXP), 1024, 0, stream>>>(xb, w1p, w2p, ib1, ib2, cnt, ltok, lwt, out);
}

// Round 4
// 461.434 us; speedup vs baseline: 1.2022x; 1.2022x over previous
//
#include <hip/hip_runtime.h>
#include <hip/hip_bf16.h>
#include <stdint.h>

#define TOK   16384
#define DIM   256
#define HIDN  1024
#define OUTD  256
#define NEXP  8
#define NSH   3
#define NSLOT 11
#define TM    64
#define CH    256

typedef short bf16x8  __attribute__((ext_vector_type(8)));
typedef float f32x4   __attribute__((ext_vector_type(4)));
typedef short short4v __attribute__((ext_vector_type(4)));

// ---- workspace layout (bytes) ----
constexpr size_t XB_OFF   = 0;                                        // T*D bf16
constexpr size_t W1P_OFF  = XB_OFF  + (size_t)TOK*DIM*2;
constexpr size_t W2P_OFF  = W1P_OFF + (size_t)(NSH+NEXP)*DIM*HIDN*2;
constexpr size_t WTS_OFF  = W2P_OFF + (size_t)(NSH+NEXP)*HIDN*OUTD*2;
constexpr size_t IDS_OFF  = WTS_OFF + (size_t)TOK*2*4;
constexpr size_t CNT_OFF  = IDS_OFF + (size_t)TOK*2*4;
constexpr size_t LTOK_OFF = CNT_OFF + 256;
constexpr size_t LW_OFF   = LTOK_OFF + (size_t)NEXP*TOK*4;
constexpr size_t WS_NEED  = LW_OFF + (size_t)NEXP*TOK*4;

__device__ __forceinline__ unsigned short f2bf(float f) {
    __hip_bfloat16 h = __float2bfloat16(f);
    return *reinterpret_cast<unsigned short*>(&h);
}

__device__ __forceinline__ f32x4 mfma16(bf16x8 a, bf16x8 b, f32x4 c) {
    return __builtin_amdgcn_mfma_f32_16x16x32_bf16(a, b, c, 0, 0, 0);
}

// XOR swizzle for 64x256 bf16 tiles (row stride 512B): spreads 8 consecutive
// rows across 8 distinct 16B slots -> conflict-free b128 column-slice reads.
__device__ __forceinline__ int swz(int row, int colb) {
    return ((row << 9) + colb) ^ ((row & 7) << 4);
}

// ---- fp32 -> bf16 of X ----
__global__ void k_convert_x(const float* __restrict__ x, short* __restrict__ xb) {
    int i = blockIdx.x * 256 + threadIdx.x;
    float4 v = reinterpret_cast<const float4*>(x)[i];
    short4v o;
    o[0] = (short)f2bf(v.x); o[1] = (short)f2bf(v.y);
    o[2] = (short)f2bf(v.z); o[3] = (short)f2bf(v.w);
    reinterpret_cast<short4v*>(xb)[i] = o;
}

// ---- fp32 weights -> bf16 packed in MFMA B-fragment order ----
// elem offset = (((slot*KT + kt)*NT + nt)*64 + lane)*8 ; n=nt*16+(lane&15),
// k = kt*32 + 8*(lane>>4) + j.
__global__ void k_convert_w(const float* __restrict__ sw1, const float* __restrict__ iw1,
                            const float* __restrict__ sw2, const float* __restrict__ iw2,
                            short* __restrict__ w1p, short* __restrict__ w2p) {
    int gid = blockIdx.x * 256 + threadIdx.x;
    const int G1 = NSLOT * (DIM/32) * (HIDN/16) * 64;
    bool isW1 = gid < G1;
    int g = isW1 ? gid : gid - G1;
    int lane = g & 63;
    int gg = g >> 6;
    int NT = isW1 ? (HIDN/16) : (OUTD/16);
    int KT = isW1 ? (DIM/32)  : (HIDN/32);
    int nt = gg % NT; gg /= NT;
    int kt = gg % KT;
    int slot = gg / KT;
    int k = kt*32 + ((lane >> 4) << 3);
    int n = nt*16 + (lane & 15);
    int Nd = isW1 ? HIDN : OUTD;
    const float* src;
    if (isW1) src = (slot < NSH) ? sw1 + (size_t)slot*DIM*HIDN  : iw1 + (size_t)(slot-NSH)*DIM*HIDN;
    else      src = (slot < NSH) ? sw2 + (size_t)slot*HIDN*OUTD : iw2 + (size_t)(slot-NSH)*HIDN*OUTD;
    bf16x8 o;
    #pragma unroll
    for (int j = 0; j < 8; ++j) o[j] = (short)f2bf(src[(size_t)(k + j)*Nd + n]);
    short* dst = isW1 ? w1p : w2p;
    reinterpret_cast<bf16x8*>(dst)[g] = o;
}

// ---- gating: fp32-exact logits, top-2, renormalized, pre-scaled by 0.5 ----
__global__ void k_gate(const float* __restrict__ x, const float* __restrict__ gw,
                       const float* __restrict__ gb, float* __restrict__ wts,
                       int* __restrict__ ids) {
    int wid = threadIdx.x >> 6, lane = threadIdx.x & 63;
    int t = blockIdx.x * 4 + wid;
    const float* xr = x + (size_t)t * DIM;
    float acc[NEXP] = {0.f,0.f,0.f,0.f,0.f,0.f,0.f,0.f};
    #pragma unroll
    for (int i = 0; i < DIM/64; ++i) {
        int d = i*64 + lane;
        float xv = xr[d];
        const float* g = gw + (size_t)d * NEXP;
        #pragma unroll
        for (int e = 0; e < NEXP; ++e) acc[e] = fmaf(xv, g[e], acc[e]);
    }
    #pragma unroll
    for (int off = 32; off; off >>= 1) {
        #pragma unroll
        for (int e = 0; e < NEXP; ++e) acc[e] += __shfl_xor(acc[e], off, 64);
    }
    if (lane == 0) {
        float l[NEXP];
        #pragma unroll
        for (int e = 0; e < NEXP; ++e) l[e] = acc[e] + gb[e];
        int e0 = 0; float v0 = l[0];
        #pragma unroll
        for (int e = 1; e < NEXP; ++e) if (l[e] > v0) { v0 = l[e]; e0 = e; }
        int e1 = -1; float v1 = -1e30f;
        #pragma unroll
        for (int e = 0; e < NEXP; ++e) if (e != e0 && l[e] > v1) { v1 = l[e]; e1 = e; }
        float r = expf(v1 - v0);
        float w0 = 0.5f / (1.f + r);
        float w1 = 0.5f * r / (1.f + r);
        ids[2*t]   = e0;  ids[2*t+1] = e1;
        wts[2*t]   = w0;  wts[2*t+1] = w1;
    }
}

// ---- build per-expert token lists ----
__global__ void k_route(const int* __restrict__ ids, const float* __restrict__ wts,
                        int* __restrict__ cnt, int* __restrict__ ltok,
                        float* __restrict__ lw) {
    int t = blockIdx.x * 256 + threadIdx.x;
    #pragma unroll
    for (int k = 0; k < 2; ++k) {
        int e = ids[2*t + k];
        int p = atomicAdd(&cnt[e], 1);
        ltok[(size_t)e*TOK + p] = t;
        lw  [(size_t)e*TOK + p] = wts[2*t + k];
    }
}

// ---- mega-kernel: one (token-tile, hidden-chunk, slot) per block ----
// phase1: H = relu(X @ W1[:, chunk] + b1)*tw  (LDS)
// phase2: out += H @ W2[chunk, :]  (+ tw*b2 from chunk 0)  via atomicAdd
__global__ __launch_bounds__(512, 4) void k_moe(
    const short* __restrict__ xb, const short* __restrict__ w1p, const short* __restrict__ w2p,
    const float* __restrict__ sb1, const float* __restrict__ sb2,
    const float* __restrict__ ib1, const float* __restrict__ ib2,
    const float* __restrict__ obj, const int* __restrict__ cnt,
    const int* __restrict__ ltok, const float* __restrict__ lw,
    float* __restrict__ out)
{
    __shared__ __align__(16) char Xs[32768];   // 64 x 256 bf16, swizzled
    __shared__ __align__(16) char Hs[32768];   // 64 x 256 bf16, swizzled
    __shared__ int   tokl[TM];
    __shared__ float twl[TM];

    const int slot = blockIdx.z;               // 0..2 shared, 3..10 independent
    const int c    = blockIdx.y;               // hidden chunk (0..3)
    const int m0   = blockIdx.x * TM;
    const bool sh  = slot < NSH;
    const int e    = slot - NSH;
    int count = TOK;
    if (!sh) { count = cnt[e]; if (m0 >= count) return; }

    const int tid  = threadIdx.x;
    const int w    = tid >> 6, lane = tid & 63;
    const int wm   = w >> 2,   wn   = w & 3;
    const int lrow = lane & 15, g   = lane >> 4;

    // stage token ids + per-token combine weights
    if (tid < TM) {
        if (sh) {
            tokl[tid] = m0 + tid;
            twl[tid]  = 0.5f * obj[(size_t)(m0 + tid)*NSH + slot];
        } else {
            int p = m0 + tid;
            bool ok = p < count;
            tokl[tid] = ok ? ltok[(size_t)e*TOK + p] : 0;
            twl[tid]  = ok ? lw[(size_t)e*TOK + p] : 0.f;
        }
    }
    __syncthreads();

    // stage X tile (gathered for ind slots): 4 x 16B per thread, coalesced
    {
        int row = tid >> 3;
        int u0  = (tid & 7) * 4;
        const short* src = xb + (size_t)tokl[row] * DIM;
        #pragma unroll
        for (int i = 0; i < 4; ++i) {
            bf16x8 v = *reinterpret_cast<const bf16x8*>(src + (u0 + i) * 8);
            *reinterpret_cast<bf16x8*>(Xs + swz(row, (u0 + i) * 16)) = v;
        }
    }
    __syncthreads();

    // ---- phase 1: acc1[2][4] = X(64x256) @ W1 chunk cols (wave: 32r x 64c) ----
    f32x4 acc1[2][4] = {};
    {
        const int ntb = c*16 + wn*4;
        bf16x8 bp[4];
        #pragma unroll
        for (int n = 0; n < 4; ++n)
            bp[n] = *reinterpret_cast<const bf16x8*>(
                w1p + (((size_t)(slot*8 + 0)*64 + ntb + n)*64 + lane)*8);
        for (int kt = 0; kt < 8; ++kt) {
            bf16x8 bc[4];
            #pragma unroll
            for (int n = 0; n < 4; ++n) bc[n] = bp[n];
            if (kt < 7) {
                #pragma unroll
                for (int n = 0; n < 4; ++n)
                    bp[n] = *reinterpret_cast<const bf16x8*>(
                        w1p + (((size_t)(slot*8 + kt+1)*64 + ntb + n)*64 + lane)*8);
            }
            bf16x8 a[2];
            #pragma unroll
            for (int m = 0; m < 2; ++m)
                a[m] = *reinterpret_cast<const bf16x8*>(
                    Xs + swz(wm*32 + m*16 + lrow, kt*64 + g*16));
            #pragma unroll
            for (int m = 0; m < 2; ++m)
                #pragma unroll
                for (int n = 0; n < 4; ++n)
                    acc1[m][n] = mfma16(a[m], bc[n], acc1[m][n]);
        }
    }
    // H = relu(acc1 + b1) * tw -> LDS bf16
    {
        const float* b1 = sh ? (sb1 + slot*HIDN) : (ib1 + (size_t)e*HIDN);
        #pragma unroll
        for (int n = 0; n < 4; ++n) {
            int colc = wn*64 + n*16 + lrow;
            float bias = b1[c*CH + colc];
            #pragma unroll
            for (int m = 0; m < 2; ++m)
                #pragma unroll
                for (int r = 0; r < 4; ++r) {
                    int row = wm*32 + m*16 + g*4 + r;
                    float v = fmaxf(acc1[m][n][r] + bias, 0.f) * twl[row];
                    *reinterpret_cast<unsigned short*>(Hs + swz(row, colc*2)) = f2bf(v);
                }
        }
    }
    __syncthreads();

    // ---- phase 2: acc2[2][4] = H(64x256) @ W2 chunk rows (out cols 0..255) ----
    f32x4 acc2[2][4] = {};
    {
        const int ntb = wn*4;
        bf16x8 bp[4];
        #pragma unroll
        for (int n = 0; n < 4; ++n)
            bp[n] = *reinterpret_cast<const bf16x8*>(
                w2p + (((size_t)(slot*32 + c*8 + 0)*16 + ntb + n)*64 + lane)*8);
        for (int kt = 0; kt < 8; ++kt) {
            bf16x8 bc[4];
            #pragma unroll
            for (int n = 0; n < 4; ++n) bc[n] = bp[n];
            if (kt < 7) {
                #pragma unroll
                for (int n = 0; n < 4; ++n)
                    bp[n] = *reinterpret_cast<const bf16x8*>(
                        w2p + (((size_t)(slot*32 + c*8 + kt+1)*16 + ntb + n)*64 + lane)*8);
            }
            bf16x8 a[2];
            #pragma unroll
            for (int m = 0; m < 2; ++m)
                a[m] = *reinterpret_cast<const bf16x8*>(
                    Hs + swz(wm*32 + m*16 + lrow, kt*64 + g*16));
            #pragma unroll
            for (int m = 0; m < 2; ++m)
                #pragma unroll
                for (int n = 0; n < 4; ++n)
                    acc2[m][n] = mfma16(a[m], bc[n], acc2[m][n]);
        }
    }
    // epilogue: atomic split-K accumulate into out (+ tw*b2 once, from c==0)
    {
        const float* b2 = sh ? (sb2 + slot*OUTD) : (ib2 + (size_t)e*OUTD);
        #pragma unroll
        for (int m = 0; m < 2; ++m)
            #pragma unroll
            for (int n = 0; n < 4; ++n) {
                int col = wn*64 + n*16 + lrow;
                #pragma unroll
                for (int r = 0; r < 4; ++r) {
                    int row = wm*32 + m*16 + g*4 + r;
                    if (sh || (m0 + row < count)) {
                        int t = tokl[row];
                        float v = acc2[m][n][r];
                        if (c == 0) v += twl[row] * b2[col];
                        atomicAdd(&out[(size_t)t*OUTD + col], v);
                    }
                }
            }
    }
}

extern "C" void kernel_launch(void* const* d_in, const int* in_sizes, int n_in,
                              void* d_out, int out_size, void* d_ws, size_t ws_size,
                              hipStream_t stream) {
    const float* x   = (const float*)d_in[0];
    const float* obj = (const float*)d_in[1];
    const float* gw  = (const float*)d_in[2];
    const float* gb  = (const float*)d_in[3];
    const float* sw1 = (const float*)d_in[4];
    const float* sb1 = (const float*)d_in[5];
    const float* sw2 = (const float*)d_in[6];
    const float* sb2 = (const float*)d_in[7];
    const float* iw1 = (const float*)d_in[8];
    const float* ib1 = (const float*)d_in[9];
    const float* iw2 = (const float*)d_in[10];
    const float* ib2 = (const float*)d_in[11];
    float* out = (float*)d_out;
    char* ws = (char*)d_ws;
    if (ws_size < WS_NEED) return;

    short* xb   = (short*)(ws + XB_OFF);
    short* w1p  = (short*)(ws + W1P_OFF);
    short* w2p  = (short*)(ws + W2P_OFF);
    float* wts  = (float*)(ws + WTS_OFF);
    int*   ids  = (int*)  (ws + IDS_OFF);
    int*   cnt  = (int*)  (ws + CNT_OFF);
    int*   ltok = (int*)  (ws + LTOK_OFF);
    float* lwt  = (float*)(ws + LW_OFF);

    hipMemsetAsync(ws + CNT_OFF, 0, 256, stream);
    hipMemsetAsync(out, 0, (size_t)out_size * 4, stream);
    k_convert_x<<<(TOK*DIM/4)/256, 256, 0, stream>>>(x, xb);
    {
        const int G = NSLOT * ((DIM/32)*(HIDN/16) + (HIDN/32)*(OUTD/16)) * 64;
        k_convert_w<<<G/256, 256, 0, stream>>>(sw1, iw1, sw2, iw2, w1p, w2p);
    }
    k_gate<<<TOK/4, 256, 0, stream>>>(x, gw, gb, wts, ids);
    k_route<<<TOK/256, 256, 0, stream>>>(ids, wts, cnt, ltok, lwt);
    k_moe<<<dim3(TOK/TM, HIDN/CH, NSLOT), 512, 0, stream>>>(
        xb, w1p, w2p, sb1, sb2, ib1, ib2, obj, cnt, ltok, lwt, out);
}